// Round 8
// baseline (238.321 us; speedup 1.0000x reference)
//
#include <hip/hip_runtime.h>
#include <stdint.h>
#include <stddef.h>

#define Bsz 2
#define Ssz 4096
#define Csz 640
#define Hn 10
#define Dh 64
#define NSPLIT 4
#define QROWS 81920   // B*H*S = 20*4096
#define NITEMS 2560   // 32 x-blocks * 20 bh * NSPLIT
#define PBLOCKS 1024  // persistent grid: 256 CU * 4 blocks/CU

typedef __attribute__((ext_vector_type(8))) short bf16x8;
typedef __attribute__((ext_vector_type(4))) float f32x4;
typedef __attribute__((ext_vector_type(16))) float f32x16;
typedef __attribute__((ext_vector_type(2))) unsigned int u32x2;
typedef __attribute__((ext_vector_type(2))) float f32x2;

typedef __attribute__((address_space(1))) void as1_void;
typedef __attribute__((address_space(3))) void as3_void;

__device__ __forceinline__ void async16(const void* g, void* l) {
  __builtin_amdgcn_global_load_lds((as1_void*)(g), (as3_void*)(l), 16, 0, 0);
}

__device__ __forceinline__ ushort f2bf(float f) {
  union { float f; uint32_t u; } v; v.f = f;
  return (ushort)((v.u + 0x7FFFu + ((v.u >> 16) & 1u)) >> 16);
}

// pack two fp32 -> bf16x2 (truncation) in one v_perm_b32
__device__ __forceinline__ uint32_t pack_bf16(float lo, float hi) {
  return __builtin_amdgcn_perm(__float_as_uint(hi), __float_as_uint(lo), 0x07060302u);
}

__device__ __forceinline__ float bf_lo(uint32_t u) {
  return __uint_as_float(u << 16);
}
__device__ __forceinline__ float bf_hi(uint32_t u) {
  return __uint_as_float(u & 0xFFFF0000u);
}

// one-instruction exp2
__device__ __forceinline__ float fast_exp2(float x) {
#if __has_builtin(__builtin_amdgcn_exp2f)
  return __builtin_amdgcn_exp2f(x);
#else
  return __exp2f(x);
#endif
}

// scale folded into Q: 1/sqrt(64) * log2(e)
#define QSCALE 0.1803368801111204f

// fused fp32->bf16 conversion: blocks [0,5120) convert hidden_states
// (1310720 float4), blocks [5120,6720) convert the 4 weight matrices
// (400 blocks each). One launch instead of two.
__global__ __launch_bounds__(256) void cvt_all(
    const float* __restrict__ hs, const float* __restrict__ Wq,
    const float* __restrict__ Wk, const float* __restrict__ Wv,
    const float* __restrict__ Wo, ushort* __restrict__ Xbf,
    ushort* __restrict__ Wqb, ushort* __restrict__ Wkb,
    ushort* __restrict__ Wvb, ushort* __restrict__ Wob)
{
  int gb = blockIdx.x;
  const float* in;
  ushort* out;
  int i;
  if (gb < 5120) {
    in = hs; out = Xbf;
    i = gb * 256 + threadIdx.x;          // < 1310720 exactly
  } else {
    int wj = gb - 5120;                  // [0,1600)
    int mat = wj / 400;
    int rb = wj - mat * 400;
    in  = (mat == 0) ? Wq  : (mat == 1) ? Wk  : (mat == 2) ? Wv  : Wo;
    out = (mat == 0) ? Wqb : (mat == 1) ? Wkb : (mat == 2) ? Wvb : Wob;
    i = rb * 256 + threadIdx.x;          // < 102400 exactly
  }
  const float4 v = ((const float4*)in)[i];
  ushort4 o;
  o.x = f2bf(v.x); o.y = f2bf(v.y); o.z = f2bf(v.z); o.w = f2bf(v.w);
  ((ushort4*)out)[i] = o;
}

// C = A(bf16 [M,640]) * W^T(bf16 [N,640]); 128x128 tile, BK=64, 4 waves.
// MODE 0: QKV fused (blockIdx.y: 0-4 Q, 5-9 K, 10-14 V). Q/K -> [B,H,S,64] (Q pre-scaled
//         by QSCALE), V -> [B,H,64,S].
// MODE 1: out-proj + bias + residual -> fp32 [B,S,C].
template<int MODE>
__global__ __launch_bounds__(256) void gemm_k(
    const ushort* __restrict__ A, const ushort* __restrict__ W0,
    const ushort* __restrict__ W1, const ushort* __restrict__ W2,
    ushort* __restrict__ Qh, ushort* __restrict__ Kh, ushort* __restrict__ Vt,
    const float* __restrict__ bias, const float* __restrict__ residual,
    float* __restrict__ outf)
{
  __shared__ ushort As[128 * 64];
  __shared__ ushort Bs[128 * 64];
  const int t = threadIdx.x;
  const int lane = t & 63;
  const int w = t >> 6;
  const int quad = lane >> 4;
  const int l15 = lane & 15;
  const int m0 = blockIdx.x * 128;
  const int wub = t & ~63;

  int n0, mat;
  const ushort* W;
  if (MODE == 0) {
    mat = blockIdx.y / 5;
    n0 = (blockIdx.y % 5) * 128;
    W = (mat == 0) ? W0 : ((mat == 1) ? W1 : W2);
  } else {
    mat = 0;
    n0 = blockIdx.y * 128;
    W = W0;
  }
  const int qm = (w >> 1) * 64;
  const int qn = (w & 1) * 64;

  f32x4 acc[4][4];
  const f32x4 zero4 = {0.f, 0.f, 0.f, 0.f};
#pragma unroll
  for (int i = 0; i < 4; ++i)
#pragma unroll
    for (int j = 0; j < 4; ++j) acc[i][j] = zero4;

  for (int k0 = 0; k0 < Csz; k0 += 64) {
    __syncthreads();
#pragma unroll
    for (int s = 0; s < 4; ++s) {
      int L = s * 256 + t;
      int row = L >> 3, pc = L & 7;
      int c = pc ^ (row & 7);
      async16(A + (size_t)(m0 + row) * Csz + k0 + c * 8,
              (char*)As + (s * 256 + wub) * 16);
    }
#pragma unroll
    for (int s = 0; s < 4; ++s) {
      int L = s * 256 + t;
      int row = L >> 3, pc = L & 7;
      int c = pc ^ (row & 7);
      async16(W + (size_t)(n0 + row) * Csz + k0 + c * 8,
              (char*)Bs + (s * 256 + wub) * 16);
    }
    __syncthreads();
#pragma unroll
    for (int ks = 0; ks < 2; ++ks) {
      bf16x8 af[4], bfr[4];
#pragma unroll
      for (int i = 0; i < 4; ++i) {
        int row = qm + i * 16 + l15;
        int pc = (ks * 4 + quad) ^ (row & 7);
        af[i] = *(const bf16x8*)(As + row * 64 + pc * 8);
      }
#pragma unroll
      for (int j = 0; j < 4; ++j) {
        int row = qn + j * 16 + l15;
        int pc = (ks * 4 + quad) ^ (row & 7);
        bfr[j] = *(const bf16x8*)(Bs + row * 64 + pc * 8);
      }
#pragma unroll
      for (int i = 0; i < 4; ++i)
#pragma unroll
        for (int j = 0; j < 4; ++j)
          acc[i][j] = __builtin_amdgcn_mfma_f32_16x16x32_bf16(af[i], bfr[j], acc[i][j], 0, 0, 0);
    }
  }

  if (MODE == 0) {
    if (mat < 2) {
      ushort* __restrict__ dst = (mat == 0) ? Qh : Kh;
      const float sc = (mat == 0) ? QSCALE : 1.0f;
#pragma unroll
      for (int j = 0; j < 4; ++j) {
        int n = n0 + qn + j * 16 + l15;
        int h = n >> 6, dh = n & 63;
#pragma unroll
        for (int i = 0; i < 4; ++i) {
#pragma unroll
          for (int r = 0; r < 4; ++r) {
            int m = m0 + qm + i * 16 + quad * 4 + r;
            int b = m >> 12, sidx = m & 4095;
            dst[(((size_t)b * Hn + h) * Ssz + sidx) * Dh + dh] = f2bf(acc[i][j][r] * sc);
          }
        }
      }
    } else {
#pragma unroll
      for (int j = 0; j < 4; ++j) {
        int n = n0 + qn + j * 16 + l15;
        int h = n >> 6, dh = n & 63;
#pragma unroll
        for (int i = 0; i < 4; ++i) {
          int mb = m0 + qm + i * 16 + quad * 4;
          int b = mb >> 12, sidx = mb & 4095;
          ushort4 pk;
          pk.x = f2bf(acc[i][j][0]); pk.y = f2bf(acc[i][j][1]);
          pk.z = f2bf(acc[i][j][2]); pk.w = f2bf(acc[i][j][3]);
          *(ushort4*)(Vt + (((size_t)b * Hn + h) * Dh + dh) * Ssz + sidx) = pk;
        }
      }
    }
  } else {
#pragma unroll
    for (int j = 0; j < 4; ++j) {
      int n = n0 + qn + j * 16 + l15;
      float bs = bias[n];
#pragma unroll
      for (int i = 0; i < 4; ++i) {
#pragma unroll
        for (int r = 0; r < 4; ++r) {
          int m = m0 + qm + i * 16 + quad * 4 + r;
          size_t idx = (size_t)m * Csz + n;
          outf[idx] = acc[i][j][r] + bs + residual[idx];
        }
      }
    }
  }
}

// Flash attention v14: v9 inner loop + PERSISTENT schedule.
// Ledger: v9 = 100.2us @ occ 35.6% (model: 2560 blocks / 1024 slots = 2.5
// rounds -> 41.7% ceiling, dispatch losses take it to 35.6). v10/v11/v12
// proved 4 blocks/CU is the hard residency ceiling. v13 proved moving l-sum
// to MFMA scales the critical path (+25% MFMA busy = +5us) -> reverted here.
// v14 removes the round quantization: launch exactly 1024 blocks (=256CUx4,
// all co-resident, no cross-block deps); block b statically processes items
// {b, b+1024, b+2048} of the NSPLIT=4 work list. No extra Opart memory, no
// atomics (graph-replay safe). Inter-item LDS hazard: item's last ITER ends
// barrier->vmcnt(0)->barrier->compute(buf1); next item's STAGE(0,0) writes
// buf0 whose last reader finished before that first barrier -> safe without
// an extra barrier. vmcnt(4) in the next item's first ITER is conservative
// vs the item's qf loads / epilogue stores (waits more, never less).
// Item decode keeps the XCD swizzle: item%8 is invariant per block.
__global__ __launch_bounds__(256, 4) void attn_k(
    const ushort* __restrict__ Qh, const ushort* __restrict__ Kh,
    const ushort* __restrict__ Vt, ushort* __restrict__ Opart,
    float* __restrict__ lpart)
{
  __shared__ ushort Ks[2][64 * 64];
  __shared__ ushort Vs[2][64 * 64];

  const int t = threadIdx.x;
  const int lane = t & 63;
  const int w = t >> 6;          // 0..3
  const int l31 = lane & 31;
  const int hi = lane >> 5;

  // precomputed LDS byte offsets, shared by K and V reads:
  // addr(ks) = l31*128 + ((ks*2+hi)^(l31&7))*16; tau/mt add 4096, cb adds 8192.
  int ka[4];
#pragma unroll
  for (int ks = 0; ks < 4; ++ks)
    ka[ks] = l31 * 128 + (((ks * 2 + hi) ^ (l31 & 7)) << 4);

  const int row8 = lane >> 3;    // staging row offset within 8-row group
  const int pcs = lane & 7;      // staging chunk slot

  f32x16 z16;
#pragma unroll
  for (int i = 0; i < 16; ++i) z16[i] = 0.f;

  const char* Kbase = (const char*)&Ks[0][0];
  const char* Vbase = (const char*)&Vs[0][0];

  for (int item = blockIdx.x; item < NITEMS; item += PBLOCKS) {
    // XCD-clustered decode (same bijection as v9): item = (team&7) +
    // 8*((team>>3)*32 + x); all 32 x-siblings of a team share one XCD.
    const int jj = item >> 3;
    const int x = jj & 31;
    const int team = (item & 7) + ((jj >> 5) << 3);
    const int bh = team % 20;
    const int z = team / 20;

    const size_t qk_off = (size_t)bh * Ssz * Dh;
    const size_t v_off = (size_t)bh * Dh * Ssz;
    const int qbase = x * 128 + w * 32;
    const int kvbase = z * (Ssz / NSPLIT);

    // preload Q B-frags: B[k=d][n=q], frag ks covers d = ks*16 + hi*8 + j
    bf16x8 qf[4];
    {
      int q = qbase + l31;
#pragma unroll
      for (int ks = 0; ks < 4; ++ks)
        qf[ks] = *(const bf16x8*)(Qh + qk_off + (size_t)q * Dh + ks * 16 + hi * 8);
    }

    f32x16 Oa[2];   // [mt]
    Oa[0] = z16; Oa[1] = z16;
    f32x2 lp2 = {0.f, 0.f};

    // stage this wave's share (2 K-chunks + 2 V-chunks of 1KB) of tile (kv rel)
#define STAGE(bi, kv)                                                          \
  {                                                                            \
    _Pragma("unroll") for (int s = 0; s < 2; ++s) {                            \
      int i = w * 2 + s;                                                       \
      int row = i * 8 + row8;                                                  \
      int c = pcs ^ (row & 7);                                                 \
      async16(Kh + qk_off + (size_t)(kvbase + (kv) + row) * Dh + c * 8,        \
              (char*)&Ks[bi][0] + i * 1024);                                   \
    }                                                                          \
    _Pragma("unroll") for (int s = 0; s < 2; ++s) {                            \
      int i = w * 2 + s;                                                       \
      int row = i * 8 + row8;                                                  \
      int c = pcs ^ (row & 7);                                                 \
      async16(Vt + v_off + (size_t)row * Ssz + kvbase + (kv) + c * 8,          \
              (char*)&Vs[bi][0] + i * 1024);                                   \
    }                                                                          \
  }

    STAGE(0, 0);

    // one kv-tile: barrier; prefetch next; vmcnt(4); barrier; QK->exp->PV.
    // CBO is compile-time (x2 unroll) so LDS reads fold to ka[ks]+imm.
#define ITER(IT, CB, CBO, DO_STAGE)                                            \
  {                                                                            \
    asm volatile("s_barrier" ::: "memory");                                    \
    if (DO_STAGE) {                                                            \
      STAGE((CB) ^ 1, ((IT) + 1) * 64);                                        \
      asm volatile("s_waitcnt vmcnt(4)" ::: "memory");                         \
    } else {                                                                   \
      asm volatile("s_waitcnt vmcnt(0)" ::: "memory");                         \
    }                                                                          \
    asm volatile("s_barrier" ::: "memory");                                    \
    _Pragma("unroll")                                                          \
    for (int tau = 0; tau < 2; ++tau) {                                        \
      f32x16 Sq;                                                               \
      _Pragma("unroll")                                                        \
      for (int ks = 0; ks < 4; ++ks) {                                         \
        bf16x8 kf = *(const bf16x8*)(Kbase + (CBO) + tau * 4096 + ka[ks]);     \
        Sq = __builtin_amdgcn_mfma_f32_32x32x16_bf16(                          \
            kf, qf[ks], ks == 0 ? z16 : Sq, 0, 0, 0);                          \
      }                                                                        \
      uint32_t pk[8];                                                          \
      _Pragma("unroll")                                                        \
      for (int a = 0; a < 8; ++a) {                                            \
        float p0 = fast_exp2(Sq[2 * a]);                                       \
        float p1 = fast_exp2(Sq[2 * a + 1]);                                   \
        f32x2 pp = {p0, p1};                                                   \
        lp2 += pp;                                                             \
        pk[a] = pack_bf16(p0, p1);                                             \
      }                                                                        \
      _Pragma("unroll")                                                        \
      for (int k2 = 0; k2 < 2; ++k2) {                                         \
        const int ks2 = tau * 2 + k2;                                          \
        const int bA = (2 * ks2) & 3;                                          \
        const int bB = (2 * ks2 + 1) & 3;                                      \
        u32x2 r0 = __builtin_amdgcn_permlane32_swap(pk[2 * bA],                \
                                                    pk[2 * bB], false, false); \
        u32x2 r1 = __builtin_amdgcn_permlane32_swap(pk[2 * bA + 1],            \
                                                    pk[2 * bB + 1], false, false); \
        union { uint32_t u[4]; bf16x8 v; } pu;                                 \
        pu.u[0] = r0.x; pu.u[1] = r1.x;                                        \
        pu.u[2] = r0.y; pu.u[3] = r1.y;                                        \
        bf16x8 pf = pu.v;                                                      \
        _Pragma("unroll")                                                      \
        for (int mt = 0; mt < 2; ++mt) {                                       \
          bf16x8 vfr = *(const bf16x8*)(Vbase + (CBO) + mt * 4096 + ka[ks2]);  \
          Oa[mt] = __builtin_amdgcn_mfma_f32_32x32x16_bf16(vfr, pf, Oa[mt],    \
                                                           0, 0, 0);           \
        }                                                                      \
      }                                                                        \
    }                                                                          \
  }

    const int NH = (Ssz / NSPLIT) / 128;  // 8 double-iterations
    for (int itp = 0; itp < NH; ++itp) {
      const int it0 = itp * 2;
      ITER(it0, 0, 0, 1);
      ITER(it0 + 1, 1, 8192, (itp + 1 < NH));
    }
#undef ITER
#undef STAGE

    // epilogue: write UNNORMALIZED partials; l = own half + xor-32 partner.
    const size_t prow_base = (size_t)z * QROWS + (size_t)bh * Ssz;
    float l_part = lp2.x + lp2.y;
    float l_tot = l_part + __shfl_xor(l_part, 32, 64);
    int q = qbase + l31;
    if (hi == 0) lpart[prow_base + q] = l_tot;
    ushort* dst = Opart + (prow_base + q) * 64;
#pragma unroll
    for (int mt = 0; mt < 2; ++mt) {
#pragma unroll
      for (int gg = 0; gg < 4; ++gg) {
        int dh0 = mt * 32 + 8 * gg + 4 * hi;
        uint2 val;
        val.x = pack_bf16(Oa[mt][4 * gg + 0], Oa[mt][4 * gg + 1]);
        val.y = pack_bf16(Oa[mt][4 * gg + 2], Oa[mt][4 * gg + 3]);
        *(uint2*)(dst + dh0) = val;
      }
    }
  }
}

// sum NSPLIT partials, normalize by total l, scatter to attnb [B,S,C] bf16
__global__ __launch_bounds__(256) void combine_k(
    const ushort* __restrict__ Opart, const float* __restrict__ lpart,
    ushort* __restrict__ attnb)
{
  int gid = blockIdx.x * 256 + threadIdx.x;   // QROWS*16 total
  int row = gid >> 4;                         // 0..QROWS-1
  int dh0 = (gid & 15) * 4;
  int bh = row >> 12, q = row & 4095;
  int b = bh / Hn, h = bh % Hn;
  float a0 = 0.f, a1 = 0.f, a2 = 0.f, a3 = 0.f, lsum = 0.f;
#pragma unroll
  for (int sp = 0; sp < NSPLIT; ++sp) {
    uint2 v = *(const uint2*)(Opart + ((size_t)sp * QROWS + row) * 64 + dh0);
    a0 += bf_lo(v.x); a1 += bf_hi(v.x);
    a2 += bf_lo(v.y); a3 += bf_hi(v.y);
    lsum += lpart[(size_t)sp * QROWS + row];
  }
  float inv = 1.0f / lsum;
  uint2 o;
  o.x = pack_bf16(a0 * inv, a1 * inv);
  o.y = pack_bf16(a2 * inv, a3 * inv);
  *(uint2*)(attnb + ((size_t)b * Ssz + q) * Csz + h * Dh + dh0) = o;
}

extern "C" void kernel_launch(void* const* d_in, const int* in_sizes, int n_in,
                              void* d_out, int out_size, void* d_ws, size_t ws_size,
                              hipStream_t stream) {
  (void)in_sizes; (void)n_in; (void)out_size; (void)ws_size;
  const float* hs = (const float*)d_in[0];
  const float* Wq = (const float*)d_in[1];
  const float* Wk = (const float*)d_in[2];
  const float* Wv = (const float*)d_in[3];
  const float* Wo = (const float*)d_in[4];
  const float* bo = (const float*)d_in[5];
  float* out = (float*)d_out;

  char* ws = (char*)d_ws;
  ushort* Xbf = (ushort*)(ws);                               // 10485760 B
  ushort* Wqb = (ushort*)(ws + 10485760);                    // 819200 B each
  ushort* Wkb = (ushort*)(ws + 10485760 + 819200);
  ushort* Wvb = (ushort*)(ws + 10485760 + 2 * 819200);
  ushort* Wob = (ushort*)(ws + 10485760 + 3 * 819200);
  ushort* Qh  = (ushort*)(ws + 13762560);                    // [20,4096,64]
  ushort* Kh  = (ushort*)(ws + 13762560 + 10485760);
  ushort* Vt  = (ushort*)(ws + 13762560 + 2 * 10485760);     // [20,64,4096]
  ushort* attnb = (ushort*)(ws + 13762560 + 3 * 10485760);   // [8192,640]
  ushort* Opart = (ushort*)(ws + 55705600);                  // [4][81920][64] bf16 = 41.9MB
  float*  lpart = (float*)(ws + 55705600 + 41943040);        // [4][81920] f32

  hipLaunchKernelGGL(cvt_all, dim3(6720), dim3(256), 0, stream,
                     hs, Wq, Wk, Wv, Wo, Xbf, Wqb, Wkb, Wvb, Wob);

  hipLaunchKernelGGL((gemm_k<0>), dim3(64, 15), dim3(256), 0, stream,
                     Xbf, Wqb, Wkb, Wvb, Qh, Kh, Vt, (const float*)nullptr,
                     (const float*)nullptr, (float*)nullptr);
  hipLaunchKernelGGL(attn_k, dim3(PBLOCKS), dim3(256), 0, stream,
                     Qh, Kh, Vt, Opart, lpart);
  hipLaunchKernelGGL(combine_k, dim3(QROWS / 16), dim3(256), 0, stream,
                     Opart, lpart, attnb);
  hipLaunchKernelGGL((gemm_k<1>), dim3(64, 5), dim3(256), 0, stream,
                     attnb, Wob, (const ushort*)nullptr, (const ushort*)nullptr,
                     (ushort*)nullptr, (ushort*)nullptr, (ushort*)nullptr,
                     bo, hs, out);
}

// Round 9
// 230.788 us; speedup vs baseline: 1.0326x; 1.0326x over previous
//
#include <hip/hip_runtime.h>
#include <stdint.h>
#include <stddef.h>

#define Bsz 2
#define Ssz 4096
#define Csz 640
#define Hn 10
#define Dh 64
#define NSPLIT 2
#define QROWS 81920   // B*H*S = 20*4096
#define NITEMS 1280   // 32 x-blocks * 20 bh * NSPLIT
#define PBLOCKS 1024  // persistent grid: 256 CU * 4 blocks/CU

typedef __attribute__((ext_vector_type(8))) short bf16x8;
typedef __attribute__((ext_vector_type(4))) float f32x4;
typedef __attribute__((ext_vector_type(16))) float f32x16;
typedef __attribute__((ext_vector_type(2))) unsigned int u32x2;
typedef __attribute__((ext_vector_type(2))) float f32x2;

typedef __attribute__((address_space(1))) void as1_void;
typedef __attribute__((address_space(3))) void as3_void;

__device__ __forceinline__ void async16(const void* g, void* l) {
  __builtin_amdgcn_global_load_lds((as1_void*)(g), (as3_void*)(l), 16, 0, 0);
}

__device__ __forceinline__ ushort f2bf(float f) {
  union { float f; uint32_t u; } v; v.f = f;
  return (ushort)((v.u + 0x7FFFu + ((v.u >> 16) & 1u)) >> 16);
}

// pack two fp32 -> bf16x2 (truncation) in one v_perm_b32
__device__ __forceinline__ uint32_t pack_bf16(float lo, float hi) {
  return __builtin_amdgcn_perm(__float_as_uint(hi), __float_as_uint(lo), 0x07060302u);
}

__device__ __forceinline__ float bf_lo(uint32_t u) {
  return __uint_as_float(u << 16);
}
__device__ __forceinline__ float bf_hi(uint32_t u) {
  return __uint_as_float(u & 0xFFFF0000u);
}

// one-instruction exp2
__device__ __forceinline__ float fast_exp2(float x) {
#if __has_builtin(__builtin_amdgcn_exp2f)
  return __builtin_amdgcn_exp2f(x);
#else
  return __exp2f(x);
#endif
}

// scale folded into Q: 1/sqrt(64) * log2(e)
#define QSCALE 0.1803368801111204f

// fused fp32->bf16 conversion: blocks [0,5120) convert hidden_states
// (1310720 float4), blocks [5120,6720) convert the 4 weight matrices
// (400 blocks each). One launch instead of two.
__global__ __launch_bounds__(256) void cvt_all(
    const float* __restrict__ hs, const float* __restrict__ Wq,
    const float* __restrict__ Wk, const float* __restrict__ Wv,
    const float* __restrict__ Wo, ushort* __restrict__ Xbf,
    ushort* __restrict__ Wqb, ushort* __restrict__ Wkb,
    ushort* __restrict__ Wvb, ushort* __restrict__ Wob)
{
  int gb = blockIdx.x;
  const float* in;
  ushort* out;
  int i;
  if (gb < 5120) {
    in = hs; out = Xbf;
    i = gb * 256 + threadIdx.x;          // < 1310720 exactly
  } else {
    int wj = gb - 5120;                  // [0,1600)
    int mat = wj / 400;
    int rb = wj - mat * 400;
    in  = (mat == 0) ? Wq  : (mat == 1) ? Wk  : (mat == 2) ? Wv  : Wo;
    out = (mat == 0) ? Wqb : (mat == 1) ? Wkb : (mat == 2) ? Wvb : Wob;
    i = rb * 256 + threadIdx.x;          // < 102400 exactly
  }
  const float4 v = ((const float4*)in)[i];
  ushort4 o;
  o.x = f2bf(v.x); o.y = f2bf(v.y); o.z = f2bf(v.z); o.w = f2bf(v.w);
  ((ushort4*)out)[i] = o;
}

// C = A(bf16 [M,640]) * W^T(bf16 [N,640]); 128x128 tile, BK=64, 4 waves.
// MODE 0: QKV fused (blockIdx.y: 0-4 Q, 5-9 K, 10-14 V). Q/K -> [B,H,S,64]
//   (Q pre-scaled by QSCALE), V -> [B,H,64,S]. v15: epilogue stages each
//   wave's 64x64 quadrant in its own 8KB of the (reused) staging LDS with a
//   16B-chunk XOR swizzle (c = k ^ (row&7)), then writes 8 rows x 128B per
//   instruction: V becomes 1KB-contiguous bursts along s (was 8B scatters at
//   8KB stride = 12.5% write eff), Q/K become 128B dh-rows (was 32B segs).
// MODE 1: out-proj + bias + residual -> fp32 [B,S,C] (direct, 64B segs ok).
template<int MODE>
__global__ __launch_bounds__(256) void gemm_k(
    const ushort* __restrict__ A, const ushort* __restrict__ W0,
    const ushort* __restrict__ W1, const ushort* __restrict__ W2,
    ushort* __restrict__ Qh, ushort* __restrict__ Kh, ushort* __restrict__ Vt,
    const float* __restrict__ bias, const float* __restrict__ residual,
    float* __restrict__ outf)
{
  __shared__ ushort SH[128 * 64 * 2];    // As = SH, Bs = SH+8192 (32KB)
  ushort* As = SH;
  ushort* Bs = SH + 8192;
  const int t = threadIdx.x;
  const int lane = t & 63;
  const int w = t >> 6;
  const int quad = lane >> 4;
  const int l15 = lane & 15;
  const int m0 = blockIdx.x * 128;
  const int wub = t & ~63;

  int n0, mat;
  const ushort* W;
  if (MODE == 0) {
    mat = blockIdx.y / 5;
    n0 = (blockIdx.y % 5) * 128;
    W = (mat == 0) ? W0 : ((mat == 1) ? W1 : W2);
  } else {
    mat = 0;
    n0 = blockIdx.y * 128;
    W = W0;
  }
  const int qm = (w >> 1) * 64;
  const int qn = (w & 1) * 64;

  f32x4 acc[4][4];
  const f32x4 zero4 = {0.f, 0.f, 0.f, 0.f};
#pragma unroll
  for (int i = 0; i < 4; ++i)
#pragma unroll
    for (int j = 0; j < 4; ++j) acc[i][j] = zero4;

  for (int k0 = 0; k0 < Csz; k0 += 64) {
    __syncthreads();
#pragma unroll
    for (int s = 0; s < 4; ++s) {
      int L = s * 256 + t;
      int row = L >> 3, pc = L & 7;
      int c = pc ^ (row & 7);
      async16(A + (size_t)(m0 + row) * Csz + k0 + c * 8,
              (char*)As + (s * 256 + wub) * 16);
    }
#pragma unroll
    for (int s = 0; s < 4; ++s) {
      int L = s * 256 + t;
      int row = L >> 3, pc = L & 7;
      int c = pc ^ (row & 7);
      async16(W + (size_t)(n0 + row) * Csz + k0 + c * 8,
              (char*)Bs + (s * 256 + wub) * 16);
    }
    __syncthreads();
#pragma unroll
    for (int ks = 0; ks < 2; ++ks) {
      bf16x8 af[4], bfr[4];
#pragma unroll
      for (int i = 0; i < 4; ++i) {
        int row = qm + i * 16 + l15;
        int pc = (ks * 4 + quad) ^ (row & 7);
        af[i] = *(const bf16x8*)(As + row * 64 + pc * 8);
      }
#pragma unroll
      for (int j = 0; j < 4; ++j) {
        int row = qn + j * 16 + l15;
        int pc = (ks * 4 + quad) ^ (row & 7);
        bfr[j] = *(const bf16x8*)(Bs + row * 64 + pc * 8);
      }
#pragma unroll
      for (int i = 0; i < 4; ++i)
#pragma unroll
        for (int j = 0; j < 4; ++j)
          acc[i][j] = __builtin_amdgcn_mfma_f32_16x16x32_bf16(af[i], bfr[j], acc[i][j], 0, 0, 0);
    }
  }

  if (MODE == 0) {
    // WAR: all waves done reading As/Bs before we reuse the LDS
    __syncthreads();
    ushort* Tw = SH + w * 4096;   // per-wave 64x64 staging, rows of 64 ushorts
    const int b = m0 >> 12;
    const int sbase = (m0 & 4095) + qm;
    const int rl = lane >> 3;     // out-pass: row-in-group 0..7
    const int ck = lane & 7;      // out-pass: 16B chunk 0..7

    if (mat < 2) {
      // T[m][n], chunk-swizzled: column byte-chunk c = (n>>3) ^ (m&7)
      const float sc = (mat == 0) ? QSCALE : 1.0f;
#pragma unroll
      for (int j = 0; j < 4; ++j) {
        int nl = j * 16 + l15;
        int cn = nl >> 3, on = nl & 7;
#pragma unroll
        for (int i = 0; i < 4; ++i) {
#pragma unroll
          for (int r = 0; r < 4; ++r) {
            int ml = i * 16 + quad * 4 + r;
            Tw[ml * 64 + (((cn ^ (ml & 7)) << 3) | on)] = f2bf(acc[i][j][r] * sc);
          }
        }
      }
      // out: row = m (s); 128B of dh contiguous per row; 8 rows/instr = 1KB
      ushort* __restrict__ dstp = (mat == 0) ? Qh : Kh;
      const int h = (n0 + qn) >> 6;      // single head per wave quadrant
      const size_t base = ((size_t)(b * Hn + h) * Ssz + sbase) * Dh;
#pragma unroll
      for (int p = 0; p < 8; ++p) {
        int row = p * 8 + rl;
        uint4 vdat = *(const uint4*)(Tw + row * 64 + ((ck ^ (row & 7)) << 3));
        *(uint4*)(dstp + base + (size_t)row * Dh + ck * 8) = vdat;
      }
    } else {
      // V: T[n][m] (transposed), ushort4 along m; chunk c = (m>>3) ^ (n&7)
#pragma unroll
      for (int j = 0; j < 4; ++j) {
        int nl = j * 16 + l15;
#pragma unroll
        for (int i = 0; i < 4; ++i) {
          int ml = i * 16 + quad * 4;
          int cm = ml >> 3, om = ml & 7;   // om in {0,4}
          ushort4 pk4;
          pk4.x = f2bf(acc[i][j][0]); pk4.y = f2bf(acc[i][j][1]);
          pk4.z = f2bf(acc[i][j][2]); pk4.w = f2bf(acc[i][j][3]);
          *(ushort4*)(Tw + nl * 64 + (((cm ^ (nl & 7)) << 3) | om)) = pk4;
        }
      }
      // out: row = n (dh); 128B of s contiguous per row
      const int h = (n0 + qn) >> 6;      // single head per wave quadrant
      const size_t base = (size_t)(b * Hn + h) * Dh * Ssz + sbase;
#pragma unroll
      for (int p = 0; p < 8; ++p) {
        int row = p * 8 + rl;            // dh = row (qn offset is head-aligned)
        uint4 vdat = *(const uint4*)(Tw + row * 64 + ((ck ^ (row & 7)) << 3));
        *(uint4*)(Vt + base + (size_t)row * Ssz + ck * 8) = vdat;
      }
    }
  } else {
#pragma unroll
    for (int j = 0; j < 4; ++j) {
      int n = n0 + qn + j * 16 + l15;
      float bs = bias[n];
#pragma unroll
      for (int i = 0; i < 4; ++i) {
#pragma unroll
        for (int r = 0; r < 4; ++r) {
          int m = m0 + qm + i * 16 + quad * 4 + r;
          size_t idx = (size_t)m * Csz + n;
          outf[idx] = acc[i][j][r] + bs + residual[idx];
        }
      }
    }
  }
}

// Flash attention v15: v14 persistent structure + NSPLIT=2.
// v14 post-mortem: persistence == v9 (101.7 vs 100.2, occ 36) -> the 36%
// occupancy is INTRINSIC (barrier/vmcnt drain vs the 50% 4-block ceiling),
// not round quantization. Seven schedule variants converge at ~100us: this
// structure's floor. NSPLIT=2 is now safe under the persistent grid (1280
// items / 1024 blocks = 1 heavy + 3 light per CU, balanced): halves Opart
// traffic (42->21MB written+read), halves combine_k, halves epilogues.
__global__ __launch_bounds__(256, 4) void attn_k(
    const ushort* __restrict__ Qh, const ushort* __restrict__ Kh,
    const ushort* __restrict__ Vt, ushort* __restrict__ Opart,
    float* __restrict__ lpart)
{
  __shared__ ushort Ks[2][64 * 64];
  __shared__ ushort Vs[2][64 * 64];

  const int t = threadIdx.x;
  const int lane = t & 63;
  const int w = t >> 6;          // 0..3
  const int l31 = lane & 31;
  const int hi = lane >> 5;

  // precomputed LDS byte offsets, shared by K and V reads:
  // addr(ks) = l31*128 + ((ks*2+hi)^(l31&7))*16; tau/mt add 4096, cb adds 8192.
  int ka[4];
#pragma unroll
  for (int ks = 0; ks < 4; ++ks)
    ka[ks] = l31 * 128 + (((ks * 2 + hi) ^ (l31 & 7)) << 4);

  const int row8 = lane >> 3;    // staging row offset within 8-row group
  const int pcs = lane & 7;      // staging chunk slot

  f32x16 z16;
#pragma unroll
  for (int i = 0; i < 16; ++i) z16[i] = 0.f;

  const char* Kbase = (const char*)&Ks[0][0];
  const char* Vbase = (const char*)&Vs[0][0];

  for (int item = blockIdx.x; item < NITEMS; item += PBLOCKS) {
    // XCD-clustered decode: item = (team&7) + 8*((team>>3)*32 + x); all 32
    // x-siblings of a team share one XCD. team in [0,40) -> (bh, z).
    const int jj = item >> 3;
    const int x = jj & 31;
    const int team = (item & 7) + ((jj >> 5) << 3);
    const int bh = team % 20;
    const int z = team / 20;

    const size_t qk_off = (size_t)bh * Ssz * Dh;
    const size_t v_off = (size_t)bh * Dh * Ssz;
    const int qbase = x * 128 + w * 32;
    const int kvbase = z * (Ssz / NSPLIT);

    // preload Q B-frags: B[k=d][n=q], frag ks covers d = ks*16 + hi*8 + j
    bf16x8 qf[4];
    {
      int q = qbase + l31;
#pragma unroll
      for (int ks = 0; ks < 4; ++ks)
        qf[ks] = *(const bf16x8*)(Qh + qk_off + (size_t)q * Dh + ks * 16 + hi * 8);
    }

    f32x16 Oa[2];   // [mt]
    Oa[0] = z16; Oa[1] = z16;
    f32x2 lp2 = {0.f, 0.f};

    // stage this wave's share (2 K-chunks + 2 V-chunks of 1KB) of tile (kv rel)
#define STAGE(bi, kv)                                                          \
  {                                                                            \
    _Pragma("unroll") for (int s = 0; s < 2; ++s) {                            \
      int i = w * 2 + s;                                                       \
      int row = i * 8 + row8;                                                  \
      int c = pcs ^ (row & 7);                                                 \
      async16(Kh + qk_off + (size_t)(kvbase + (kv) + row) * Dh + c * 8,        \
              (char*)&Ks[bi][0] + i * 1024);                                   \
    }                                                                          \
    _Pragma("unroll") for (int s = 0; s < 2; ++s) {                            \
      int i = w * 2 + s;                                                       \
      int row = i * 8 + row8;                                                  \
      int c = pcs ^ (row & 7);                                                 \
      async16(Vt + v_off + (size_t)row * Ssz + kvbase + (kv) + c * 8,          \
              (char*)&Vs[bi][0] + i * 1024);                                   \
    }                                                                          \
  }

    STAGE(0, 0);

    // one kv-tile: barrier; prefetch next; vmcnt(4); barrier; QK->exp->PV.
    // CBO is compile-time (x2 unroll) so LDS reads fold to ka[ks]+imm.
#define ITER(IT, CB, CBO, DO_STAGE)                                            \
  {                                                                            \
    asm volatile("s_barrier" ::: "memory");                                    \
    if (DO_STAGE) {                                                            \
      STAGE((CB) ^ 1, ((IT) + 1) * 64);                                        \
      asm volatile("s_waitcnt vmcnt(4)" ::: "memory");                         \
    } else {                                                                   \
      asm volatile("s_waitcnt vmcnt(0)" ::: "memory");                         \
    }                                                                          \
    asm volatile("s_barrier" ::: "memory");                                    \
    _Pragma("unroll")                                                          \
    for (int tau = 0; tau < 2; ++tau) {                                        \
      f32x16 Sq;                                                               \
      _Pragma("unroll")                                                        \
      for (int ks = 0; ks < 4; ++ks) {                                         \
        bf16x8 kf = *(const bf16x8*)(Kbase + (CBO) + tau * 4096 + ka[ks]);     \
        Sq = __builtin_amdgcn_mfma_f32_32x32x16_bf16(                          \
            kf, qf[ks], ks == 0 ? z16 : Sq, 0, 0, 0);                          \
      }                                                                        \
      uint32_t pk[8];                                                          \
      _Pragma("unroll")                                                        \
      for (int a = 0; a < 8; ++a) {                                            \
        float p0 = fast_exp2(Sq[2 * a]);                                       \
        float p1 = fast_exp2(Sq[2 * a + 1]);                                   \
        f32x2 pp = {p0, p1};                                                   \
        lp2 += pp;                                                             \
        pk[a] = pack_bf16(p0, p1);                                             \
      }                                                                        \
      _Pragma("unroll")                                                        \
      for (int k2 = 0; k2 < 2; ++k2) {                                         \
        const int ks2 = tau * 2 + k2;                                          \
        const int bA = (2 * ks2) & 3;                                          \
        const int bB = (2 * ks2 + 1) & 3;                                      \
        u32x2 r0 = __builtin_amdgcn_permlane32_swap(pk[2 * bA],                \
                                                    pk[2 * bB], false, false); \
        u32x2 r1 = __builtin_amdgcn_permlane32_swap(pk[2 * bA + 1],            \
                                                    pk[2 * bB + 1], false, false); \
        union { uint32_t u[4]; bf16x8 v; } pu;                                 \
        pu.u[0] = r0.x; pu.u[1] = r1.x;                                        \
        pu.u[2] = r0.y; pu.u[3] = r1.y;                                        \
        bf16x8 pf = pu.v;                                                      \
        _Pragma("unroll")                                                      \
        for (int mt = 0; mt < 2; ++mt) {                                       \
          bf16x8 vfr = *(const bf16x8*)(Vbase + (CBO) + mt * 4096 + ka[ks2]);  \
          Oa[mt] = __builtin_amdgcn_mfma_f32_32x32x16_bf16(vfr, pf, Oa[mt],    \
                                                           0, 0, 0);           \
        }                                                                      \
      }                                                                        \
    }                                                                          \
  }

    const int NH = (Ssz / NSPLIT) / 128;  // 16 double-iterations
    for (int itp = 0; itp < NH; ++itp) {
      const int it0 = itp * 2;
      ITER(it0, 0, 0, 1);
      ITER(it0 + 1, 1, 8192, (itp + 1 < NH));
    }
#undef ITER
#undef STAGE

    // epilogue: write UNNORMALIZED partials; l = own half + xor-32 partner.
    const size_t prow_base = (size_t)z * QROWS + (size_t)bh * Ssz;
    float l_part = lp2.x + lp2.y;
    float l_tot = l_part + __shfl_xor(l_part, 32, 64);
    int q = qbase + l31;
    if (hi == 0) lpart[prow_base + q] = l_tot;
    ushort* dst = Opart + (prow_base + q) * 64;
#pragma unroll
    for (int mt = 0; mt < 2; ++mt) {
#pragma unroll
      for (int gg = 0; gg < 4; ++gg) {
        int dh0 = mt * 32 + 8 * gg + 4 * hi;
        uint2 val;
        val.x = pack_bf16(Oa[mt][4 * gg + 0], Oa[mt][4 * gg + 1]);
        val.y = pack_bf16(Oa[mt][4 * gg + 2], Oa[mt][4 * gg + 3]);
        *(uint2*)(dst + dh0) = val;
      }
    }
  }
}

// sum NSPLIT partials, normalize by total l, scatter to attnb [B,S,C] bf16
__global__ __launch_bounds__(256) void combine_k(
    const ushort* __restrict__ Opart, const float* __restrict__ lpart,
    ushort* __restrict__ attnb)
{
  int gid = blockIdx.x * 256 + threadIdx.x;   // QROWS*16 total
  int row = gid >> 4;                         // 0..QROWS-1
  int dh0 = (gid & 15) * 4;
  int bh = row >> 12, q = row & 4095;
  int b = bh / Hn, h = bh % Hn;
  float a0 = 0.f, a1 = 0.f, a2 = 0.f, a3 = 0.f, lsum = 0.f;
#pragma unroll
  for (int sp = 0; sp < NSPLIT; ++sp) {
    uint2 v = *(const uint2*)(Opart + ((size_t)sp * QROWS + row) * 64 + dh0);
    a0 += bf_lo(v.x); a1 += bf_hi(v.x);
    a2 += bf_lo(v.y); a3 += bf_hi(v.y);
    lsum += lpart[(size_t)sp * QROWS + row];
  }
  float inv = 1.0f / lsum;
  uint2 o;
  o.x = pack_bf16(a0 * inv, a1 * inv);
  o.y = pack_bf16(a2 * inv, a3 * inv);
  *(uint2*)(attnb + ((size_t)b * Ssz + q) * Csz + h * Dh + dh0) = o;
}

extern "C" void kernel_launch(void* const* d_in, const int* in_sizes, int n_in,
                              void* d_out, int out_size, void* d_ws, size_t ws_size,
                              hipStream_t stream) {
  (void)in_sizes; (void)n_in; (void)out_size; (void)ws_size;
  const float* hs = (const float*)d_in[0];
  const float* Wq = (const float*)d_in[1];
  const float* Wk = (const float*)d_in[2];
  const float* Wv = (const float*)d_in[3];
  const float* Wo = (const float*)d_in[4];
  const float* bo = (const float*)d_in[5];
  float* out = (float*)d_out;

  char* ws = (char*)d_ws;
  ushort* Xbf = (ushort*)(ws);                               // 10485760 B
  ushort* Wqb = (ushort*)(ws + 10485760);                    // 819200 B each
  ushort* Wkb = (ushort*)(ws + 10485760 + 819200);
  ushort* Wvb = (ushort*)(ws + 10485760 + 2 * 819200);
  ushort* Wob = (ushort*)(ws + 10485760 + 3 * 819200);
  ushort* Qh  = (ushort*)(ws + 13762560);                    // [20,4096,64]
  ushort* Kh  = (ushort*)(ws + 13762560 + 10485760);
  ushort* Vt  = (ushort*)(ws + 13762560 + 2 * 10485760);     // [20,64,4096]
  ushort* attnb = (ushort*)(ws + 13762560 + 3 * 10485760);   // [8192,640]
  ushort* Opart = (ushort*)(ws + 55705600);                  // [NSPLIT][81920][64] bf16
  float*  lpart = (float*)(ws + 55705600 + 41943040);        // [NSPLIT][81920] f32

  hipLaunchKernelGGL(cvt_all, dim3(6720), dim3(256), 0, stream,
                     hs, Wq, Wk, Wv, Wo, Xbf, Wqb, Wkb, Wvb, Wob);

  hipLaunchKernelGGL((gemm_k<0>), dim3(64, 15), dim3(256), 0, stream,
                     Xbf, Wqb, Wkb, Wvb, Qh, Kh, Vt, (const float*)nullptr,
                     (const float*)nullptr, (float*)nullptr);
  hipLaunchKernelGGL(attn_k, dim3(PBLOCKS), dim3(256), 0, stream,
                     Qh, Kh, Vt, Opart, lpart);
  hipLaunchKernelGGL(combine_k, dim3(QROWS / 16), dim3(256), 0, stream,
                     Opart, lpart, attnb);
  hipLaunchKernelGGL((gemm_k<1>), dim3(64, 5), dim3(256), 0, stream,
                     attnb, Wob, (const ushort*)nullptr, (const ushort*)nullptr,
                     (ushort*)nullptr, (ushort*)nullptr, (ushort*)nullptr,
                     bo, hs, out);
}